// Round 1
// 5695.018 us; speedup vs baseline: 2.4982x; 2.4982x over previous
//
#include <hip/hip_runtime.h>

// MEGConv: NA=NB=2e6, NG=2e5, D=32.
// d_out layout: atom_new[NA*32] | bond_new[NB*32] | glob_new[NG*32]  (fp32)
// Scratch: bond_sum[NA*32] lives in d_out's bond region (NB>=NA here, consumed
// before bond_new is written). d_ws holds: bcnt[NA] | asumg[NG*32] | acntg[NG]
// | bsumg[NG*32] | bcntg[NG]  (~61 MB).
//
// Atom/bond MLPs are block-tiled GEMMs: 64 rows/block staged in LDS (XOR-
// swizzled f4 slots -> conflict-free ds_read_b128), thread tile 2 rows x 8
// cols, weights streamed as lane-parallel float4 from L2.

#define TPB 256
#define RB 64  // rows per block in tiled MLP kernels

__global__ void zero4_kernel(float4* __restrict__ p, long n4) {
  long i = (long)blockIdx.x * blockDim.x + threadIdx.x;
  long stride = (long)gridDim.x * blockDim.x;
  float4 z = make_float4(0.f, 0.f, 0.f, 0.f);
  for (; i < n4; i += stride) p[i] = z;
}

// One thread per (bond, dim): scatter bond feats to both endpoint atoms.
__global__ void scatter_bonds_kernel(const float* __restrict__ bf,
                                     const int* __restrict__ ba,
                                     float* __restrict__ bsum,
                                     float* __restrict__ bcnt, int NB) {
  int gid = blockIdx.x * blockDim.x + threadIdx.x;
  int b = gid >> 5;
  if (b >= NB) return;
  int d = gid & 31;
  int a0 = ba[2 * b];
  int a1 = ba[2 * b + 1];
  float v = bf[(long)b * 32 + d];
  atomicAdd(&bsum[(long)a0 * 32 + d], v);
  atomicAdd(&bsum[(long)a1 * 32 + d], v);
  if (d == 0) {
    atomicAdd(&bcnt[a0], 1.f);
    atomicAdd(&bcnt[a1], 1.f);
  }
}

__device__ __forceinline__ float softplus_f(float v) {
  // log1p(exp(v)), numerically stable
  return fmaxf(v, 0.f) + log1pf(expf(-fabsf(v)));
}

// ---------------- tiled GEMM machinery ----------------
// X tile in LDS: row-major, PITCHF floats/row, float4 slot s stored at
// physical slot (s ^ ((row>>1)&7))  -> all b128 LDS ops bank-conflict-free.
// Thread tile: rows {row0, row0+1} x TC cols starting at c0.
// W is row-major [K][NCOL] in global (L2-resident; per-wave dedup -> each W
// element fetched once per k per wave).
template <int KF4, int PITCHF, int TC, int NCOL>
__device__ __forceinline__ void gemm_tile(const float* __restrict__ Xsh,
                                          int row0, int sw,
                                          const float* __restrict__ W, int c0,
                                          float (&acc)[2][TC]) {
#pragma unroll 2
  for (int k4 = 0; k4 < KF4; ++k4) {
    float xa[4], xb[4];
    *(float4*)xa = *(const float4*)(Xsh + row0 * PITCHF + ((k4 ^ sw) << 2));
    *(float4*)xb =
        *(const float4*)(Xsh + (row0 + 1) * PITCHF + ((k4 ^ sw) << 2));
#pragma unroll
    for (int i = 0; i < 4; ++i) {
      const float* wp = W + (k4 * 4 + i) * NCOL + c0;
      float w0[4];
      *(float4*)w0 = *(const float4*)wp;
      if constexpr (TC == 8) {
        float w1[4];
        *(float4*)w1 = *(const float4*)(wp + 4);
#pragma unroll
        for (int j = 0; j < 4; ++j) {
          acc[0][j] = fmaf(xa[i], w0[j], acc[0][j]);
          acc[1][j] = fmaf(xb[i], w0[j], acc[1][j]);
          acc[0][j + 4] = fmaf(xa[i], w1[j], acc[0][j + 4]);
          acc[1][j + 4] = fmaf(xb[i], w1[j], acc[1][j + 4]);
        }
      } else {
#pragma unroll
        for (int j = 0; j < 4; ++j) {
          acc[0][j] = fmaf(xa[i], w0[j], acc[0][j]);
          acc[1][j] = fmaf(xb[i], w0[j], acc[1][j]);
        }
      }
    }
  }
}

// softplus(acc) then store 2 rows x 8 cols into LDS (pitch 64, swizzled).
__device__ __forceinline__ void store_h(float* __restrict__ Hsh, int row0,
                                        int sw, int c0, float (&acc)[2][8]) {
#pragma unroll
  for (int r = 0; r < 2; ++r) {
#pragma unroll
    for (int j = 0; j < 8; ++j) acc[r][j] = softplus_f(acc[r][j]);
#pragma unroll
    for (int p = 0; p < 2; ++p) {
      int slot = (c0 >> 2) + p;
      *(float4*)(Hsh + (row0 + r) * 64 + ((slot ^ sw) << 2)) =
          make_float4(acc[r][4 * p], acc[r][4 * p + 1], acc[r][4 * p + 2],
                      acc[r][4 * p + 3]);
    }
  }
}

// ---------------- atom MLP (K1 = 96: af | mean_bond | gf[amol]) -------------
__global__ void __launch_bounds__(TPB)
atom_mlp_kernel(const float* __restrict__ af, const float* __restrict__ bsum,
                const float* __restrict__ bcnt, const float* __restrict__ gf,
                const int* __restrict__ amol,
                const float* __restrict__ W1, const float* __restrict__ B1,
                const float* __restrict__ W2, const float* __restrict__ B2,
                const float* __restrict__ W3, const float* __restrict__ B3,
                float* __restrict__ out_atom, float* __restrict__ gsum,
                float* __restrict__ gcnt, int NA) {
  __shared__ float Xs[RB * 96];   // X tile; later reused for H2 (RB*64 prefix)
  __shared__ float H1s[RB * 64];
  __shared__ int ig[RB];
  __shared__ float rinv[RB];

  const int tid = threadIdx.x;
  const long a0base = (long)blockIdx.x * RB;
  const int valid = (NA - a0base < RB) ? (int)(NA - a0base) : RB;

  if (tid < RB) {
    long a = a0base + (tid < valid ? tid : 0);
    ig[tid] = amol[a];
    float c = bcnt[a];
    rinv[tid] = c > 0.f ? 1.f / c : 0.f;
  }
  __syncthreads();

  // stage X: valid rows x 24 f4 slots (af:0-7, bsum*inv:8-15, gf:16-23)
  for (int s = tid; s < valid * 24; s += TPB) {
    int r = s / 24;
    int slot = s - r * 24;
    int seg = slot >> 3, off = slot & 7;
    long a = a0base + r;
    float4 v;
    if (seg == 0) {
      v = ((const float4*)af)[a * 8 + off];
    } else if (seg == 1) {
      v = ((const float4*)bsum)[a * 8 + off];
      float iv = rinv[r];
      v.x *= iv; v.y *= iv; v.z *= iv; v.w *= iv;
    } else {
      v = ((const float4*)gf)[(long)ig[r] * 8 + off];
    }
    int phys = slot ^ ((r >> 1) & 7);
    *(float4*)&Xs[r * 96 + phys * 4] = v;
  }
  __syncthreads();

  const int tc = tid & 7, tr = tid >> 3;
  const int row0 = tr * 2, sw = tr & 7, c0 = tc * 8;

  float acc[2][8];
  {
    float b1[8];
    *(float4*)b1 = *(const float4*)(B1 + c0);
    *(float4*)(b1 + 4) = *(const float4*)(B1 + c0 + 4);
#pragma unroll
    for (int j = 0; j < 8; ++j) { acc[0][j] = b1[j]; acc[1][j] = b1[j]; }
  }
  gemm_tile<24, 96, 8, 64>(Xs, row0, sw, W1, c0, acc);
  store_h(H1s, row0, sw, c0, acc);
  __syncthreads();

  {
    float b2[8];
    *(float4*)b2 = *(const float4*)(B2 + c0);
    *(float4*)(b2 + 4) = *(const float4*)(B2 + c0 + 4);
#pragma unroll
    for (int j = 0; j < 8; ++j) { acc[0][j] = b2[j]; acc[1][j] = b2[j]; }
  }
  gemm_tile<16, 64, 8, 64>(H1s, row0, sw, W2, c0, acc);
  store_h(Xs, row0, sw, c0, acc);  // H2 into Xs prefix (pitch 64)
  __syncthreads();

  const int c3 = tc * 4;
  float acc3[2][4];
  {
    float b3[4];
    *(float4*)b3 = *(const float4*)(B3 + c3);
#pragma unroll
    for (int j = 0; j < 4; ++j) { acc3[0][j] = b3[j]; acc3[1][j] = b3[j]; }
  }
  gemm_tile<16, 64, 4, 32>(Xs, row0, sw, W3, c3, acc3);

#pragma unroll
  for (int r = 0; r < 2; ++r) {
    int row = row0 + r;
    if (row < valid) {
      *(float4*)(out_atom + (a0base + row) * 32 + c3) =
          make_float4(acc3[r][0], acc3[r][1], acc3[r][2], acc3[r][3]);
      int g = ig[row];
#pragma unroll
      for (int j = 0; j < 4; ++j)
        atomicAdd(&gsum[(long)g * 32 + c3 + j], acc3[r][j]);
      if (tc == 0) atomicAdd(&gcnt[g], 1.f);
    }
  }
}

// ---------------- bond MLP (K1 = 128: bf | a0 | a1 | gf[bmol]) --------------
__global__ void __launch_bounds__(TPB)
bond_mlp_kernel(const float* __restrict__ bf, const float* __restrict__ atom_new,
                const float* __restrict__ gf, const int* __restrict__ ba,
                const int* __restrict__ bmol,
                const float* __restrict__ W1, const float* __restrict__ B1,
                const float* __restrict__ W2, const float* __restrict__ B2,
                const float* __restrict__ W3, const float* __restrict__ B3,
                float* __restrict__ out_bond, float* __restrict__ gsum,
                float* __restrict__ gcnt, int NB) {
  __shared__ float Xs[RB * 128];  // X tile; later reused for H2 (RB*64 prefix)
  __shared__ float H1s[RB * 64];
  __shared__ int ia0[RB], ia1[RB], ig[RB];

  const int tid = threadIdx.x;
  const long b0 = (long)blockIdx.x * RB;
  const int valid = (NB - b0 < RB) ? (int)(NB - b0) : RB;

  if (tid < RB) {
    long b = b0 + (tid < valid ? tid : 0);
    ia0[tid] = ba[2 * b];
    ia1[tid] = ba[2 * b + 1];
    ig[tid] = bmol[b];
  }
  __syncthreads();

  // stage X: 64 rows x 32 f4 slots (bf:0-7, a0:8-15, a1:16-23, gf:24-31)
#pragma unroll
  for (int it = 0; it < 8; ++it) {
    int s = tid + it * TPB;
    int r = s >> 5, slot = s & 31;
    if (r < valid) {
      int seg = slot >> 3, off = slot & 7;
      const float4* src;
      if (seg == 0)      src = (const float4*)bf + ((b0 + r) * 8 + off);
      else if (seg == 1) src = (const float4*)atom_new + ((long)ia0[r] * 8 + off);
      else if (seg == 2) src = (const float4*)atom_new + ((long)ia1[r] * 8 + off);
      else               src = (const float4*)gf + ((long)ig[r] * 8 + off);
      int phys = slot ^ ((r >> 1) & 7);
      *(float4*)&Xs[r * 128 + phys * 4] = *src;
    }
  }
  __syncthreads();

  const int tc = tid & 7, tr = tid >> 3;
  const int row0 = tr * 2, sw = tr & 7, c0 = tc * 8;

  float acc[2][8];
  {
    float b1[8];
    *(float4*)b1 = *(const float4*)(B1 + c0);
    *(float4*)(b1 + 4) = *(const float4*)(B1 + c0 + 4);
#pragma unroll
    for (int j = 0; j < 8; ++j) { acc[0][j] = b1[j]; acc[1][j] = b1[j]; }
  }
  gemm_tile<32, 128, 8, 64>(Xs, row0, sw, W1, c0, acc);
  store_h(H1s, row0, sw, c0, acc);
  __syncthreads();

  {
    float b2[8];
    *(float4*)b2 = *(const float4*)(B2 + c0);
    *(float4*)(b2 + 4) = *(const float4*)(B2 + c0 + 4);
#pragma unroll
    for (int j = 0; j < 8; ++j) { acc[0][j] = b2[j]; acc[1][j] = b2[j]; }
  }
  gemm_tile<16, 64, 8, 64>(H1s, row0, sw, W2, c0, acc);
  store_h(Xs, row0, sw, c0, acc);  // H2 into Xs prefix (pitch 64)
  __syncthreads();

  const int c3 = tc * 4;
  float acc3[2][4];
  {
    float b3[4];
    *(float4*)b3 = *(const float4*)(B3 + c3);
#pragma unroll
    for (int j = 0; j < 4; ++j) { acc3[0][j] = b3[j]; acc3[1][j] = b3[j]; }
  }
  gemm_tile<16, 64, 4, 32>(Xs, row0, sw, W3, c3, acc3);

#pragma unroll
  for (int r = 0; r < 2; ++r) {
    int row = row0 + r;
    if (row < valid) {
      *(float4*)(out_bond + (b0 + row) * 32 + c3) =
          make_float4(acc3[r][0], acc3[r][1], acc3[r][2], acc3[r][3]);
      int g = ig[row];
#pragma unroll
      for (int j = 0; j < 4; ++j)
        atomicAdd(&gsum[(long)g * 32 + c3 + j], acc3[r][j]);
      if (tc == 0) atomicAdd(&gcnt[g], 1.f);
    }
  }
}

// ---------------- glob MLP (unchanged per-row design; NG is small) ----------
__device__ __forceinline__ void l1_chunk(float h1[64],
                                         const float* __restrict__ xrow,
                                         float scale,
                                         const float* __restrict__ Wrow) {
#pragma unroll 4
  for (int k = 0; k < 32; ++k) {
    float xv = xrow[k] * scale;
#pragma unroll
    for (int j = 0; j < 64; ++j) h1[j] = fmaf(xv, Wrow[k * 64 + j], h1[j]);
  }
}

__device__ __forceinline__ void mlp_tail(float h1[64],
                                         const float* __restrict__ W2,
                                         const float* __restrict__ B2,
                                         const float* __restrict__ W3,
                                         const float* __restrict__ B3,
                                         float o[32]) {
#pragma unroll
  for (int j = 0; j < 64; ++j) h1[j] = softplus_f(h1[j]);
  float h2[64];
#pragma unroll
  for (int j = 0; j < 64; ++j) h2[j] = B2[j];
#pragma unroll
  for (int k = 0; k < 64; ++k) {
    float xv = h1[k];
#pragma unroll
    for (int j = 0; j < 64; ++j) h2[j] = fmaf(xv, W2[k * 64 + j], h2[j]);
  }
#pragma unroll
  for (int j = 0; j < 64; ++j) h2[j] = softplus_f(h2[j]);
#pragma unroll
  for (int j = 0; j < 32; ++j) o[j] = B3[j];
#pragma unroll
  for (int k = 0; k < 64; ++k) {
    float xv = h2[k];
#pragma unroll
    for (int j = 0; j < 32; ++j) o[j] = fmaf(xv, W3[k * 32 + j], o[j]);
  }
}

__global__ void __launch_bounds__(TPB)
glob_mlp_kernel(const float* __restrict__ gf, const float* __restrict__ asum,
                const float* __restrict__ acnt, const float* __restrict__ bsum,
                const float* __restrict__ bcnt,
                const float* __restrict__ W1, const float* __restrict__ B1,
                const float* __restrict__ W2, const float* __restrict__ B2,
                const float* __restrict__ W3, const float* __restrict__ B3,
                float* __restrict__ out_glob, int NG) {
  int m = blockIdx.x * TPB + threadIdx.x;
  if (m >= NG) return;
  float h1[64];
#pragma unroll
  for (int j = 0; j < 64; ++j) h1[j] = B1[j];
  l1_chunk(h1, gf + (long)m * 32, 1.f, W1);
  float ca = acnt[m];
  float inva = ca > 0.f ? 1.f / ca : 0.f;
  l1_chunk(h1, asum + (long)m * 32, inva, W1 + 32 * 64);
  float cb = bcnt[m];
  float invb = cb > 0.f ? 1.f / cb : 0.f;
  l1_chunk(h1, bsum + (long)m * 32, invb, W1 + 64 * 64);
  float o[32];
  mlp_tail(h1, W2, B2, W3, B3, o);
  float4* dst = (float4*)(out_glob + (long)m * 32);
#pragma unroll
  for (int q = 0; q < 8; ++q)
    dst[q] = make_float4(o[4 * q], o[4 * q + 1], o[4 * q + 2], o[4 * q + 3]);
}

extern "C" void kernel_launch(void* const* d_in, const int* in_sizes, int n_in,
                              void* d_out, int out_size, void* d_ws, size_t ws_size,
                              hipStream_t stream) {
  const float* af = (const float*)d_in[0];
  const float* bf = (const float*)d_in[1];
  const float* gf = (const float*)d_in[2];
  const int* ba = (const int*)d_in[3];
  const int* amol = (const int*)d_in[4];
  const int* bmol = (const int*)d_in[5];
  const float* aW1 = (const float*)d_in[6];
  const float* ab1 = (const float*)d_in[7];
  const float* aW2 = (const float*)d_in[8];
  const float* ab2 = (const float*)d_in[9];
  const float* aW3 = (const float*)d_in[10];
  const float* ab3 = (const float*)d_in[11];
  const float* bW1 = (const float*)d_in[12];
  const float* bb1 = (const float*)d_in[13];
  const float* bW2 = (const float*)d_in[14];
  const float* bb2 = (const float*)d_in[15];
  const float* bW3 = (const float*)d_in[16];
  const float* bb3 = (const float*)d_in[17];
  const float* gW1 = (const float*)d_in[18];
  const float* gb1 = (const float*)d_in[19];
  const float* gW2 = (const float*)d_in[20];
  const float* gb2 = (const float*)d_in[21];
  const float* gW3 = (const float*)d_in[22];
  const float* gb3 = (const float*)d_in[23];

  const int NA = in_sizes[0] / 32;
  const int NB = in_sizes[1] / 32;
  const int NG = in_sizes[2] / 32;

  float* out = (float*)d_out;
  float* out_atom = out;
  float* out_bond = out + (long)NA * 32;
  float* out_glob = out + (long)NA * 32 + (long)NB * 32;

  // bond_sum scratch reuses the bond_new output region (NB*32 >= NA*32 here;
  // consumed by atom_mlp before bond_mlp overwrites it with bond_new).
  float* bsum = out_bond;
  float* ws = (float*)d_ws;
  float* bcnt = ws;                        // [NA]
  float* asumg = bcnt + (long)NA;          // [NG*32]
  float* acntg = asumg + (long)NG * 32;    // [NG]
  float* bsumg = acntg + (long)NG;         // [NG*32]
  float* bcntg = bsumg + (long)NG * 32;    // [NG]

  long z1 = ((long)NA * 32) / 4;                 // bond_sum floats /4
  long z2 = ((long)NA + (long)NG * 66 + 3) / 4;  // ws floats /4
  zero4_kernel<<<dim3(2048), dim3(TPB), 0, stream>>>((float4*)bsum, z1);
  zero4_kernel<<<dim3(2048), dim3(TPB), 0, stream>>>((float4*)ws, z2);

  long nscatter = (long)NB * 32;
  scatter_bonds_kernel<<<dim3((nscatter + TPB - 1) / TPB), dim3(TPB), 0, stream>>>(
      bf, ba, bsum, bcnt, NB);

  atom_mlp_kernel<<<dim3((NA + RB - 1) / RB), dim3(TPB), 0, stream>>>(
      af, bsum, bcnt, gf, amol, aW1, ab1, aW2, ab2, aW3, ab3, out_atom, asumg,
      acntg, NA);

  bond_mlp_kernel<<<dim3((NB + RB - 1) / RB), dim3(TPB), 0, stream>>>(
      bf, out_atom, gf, ba, bmol, bW1, bb1, bW2, bb2, bW3, bb3, out_bond, bsumg,
      bcntg, NB);

  glob_mlp_kernel<<<dim3((NG + TPB - 1) / TPB), dim3(TPB), 0, stream>>>(
      gf, asumg, acntg, bsumg, bcntg, gW1, gb1, gW2, gb2, gW3, gb3, out_glob,
      NG);
}

// Round 2
// 3995.584 us; speedup vs baseline: 3.5607x; 1.4253x over previous
//
#include <hip/hip_runtime.h>

// MEGConv: NA=NB=2e6, NG=2e5, D=32.
// d_out layout: atom_new[NA*32] | bond_new[NB*32] | glob_new[NG*32]  (fp32)
// Scratch: bond_sum[NA*32] lives in d_out's bond region (NB>=NA, consumed
// before bond_new is written). Weight bf16-split scratch (106 KB) lives in the
// out_glob region (written only by the final glob kernel). d_ws holds:
// bcnt[NA] | asumg[NG*32] | acntg[NG] | bsumg[NG*32] | bcntg[NG]  (~61 MB).
//
// Atom/bond MLPs run on MFMA (bf16 3-product split = effective fp32):
//   x = xh + xl (bf16 each); x@W ~= xh@Wh + xl@Wh + xh@Wl, fp32 accum.
// Block = 64 rows, 4 waves; wave w owns rows [16w,16w+16). X/H in LDS as
// bf16 hi/lo, pitches 136/104/72 ushorts (16B-aligned, bank-friendly).
// Weights pre-transposed+split by wsplit_kernel into [n][k] bf16 hi/lo.

#define TPB 256

typedef __attribute__((ext_vector_type(8))) short short8v;
typedef __attribute__((ext_vector_type(4))) float f32x4;

#define MFMA_BF16(A, B, C) \
  __builtin_amdgcn_mfma_f32_16x16x32_bf16((A), (B), (C), 0, 0, 0)

__global__ void zero4_kernel(float4* __restrict__ p, long n4) {
  long i = (long)blockIdx.x * blockDim.x + threadIdx.x;
  long stride = (long)gridDim.x * blockDim.x;
  float4 z = make_float4(0.f, 0.f, 0.f, 0.f);
  for (; i < n4; i += stride) p[i] = z;
}

// One thread per (bond, dim): scatter bond feats to both endpoint atoms.
__global__ void scatter_bonds_kernel(const float* __restrict__ bf,
                                     const int* __restrict__ ba,
                                     float* __restrict__ bsum,
                                     float* __restrict__ bcnt, int NB) {
  int gid = blockIdx.x * blockDim.x + threadIdx.x;
  int b = gid >> 5;
  if (b >= NB) return;
  int d = gid & 31;
  int a0 = ba[2 * b];
  int a1 = ba[2 * b + 1];
  float v = bf[(long)b * 32 + d];
  atomicAdd(&bsum[(long)a0 * 32 + d], v);
  atomicAdd(&bsum[(long)a1 * 32 + d], v);
  if (d == 0) {
    atomicAdd(&bcnt[a0], 1.f);
    atomicAdd(&bcnt[a1], 1.f);
  }
}

__device__ __forceinline__ float softplus_f(float v) {
  return fmaxf(v, 0.f) + log1pf(expf(-fabsf(v)));
}

// ---------- bf16 split helpers ----------
__device__ __forceinline__ unsigned short f2bf(float x) {
  unsigned int u = __float_as_uint(x);
  u += 0x7fffu + ((u >> 16) & 1u);
  return (unsigned short)(u >> 16);
}
__device__ __forceinline__ float bf2f(unsigned short h) {
  return __uint_as_float(((unsigned int)h) << 16);
}
__device__ __forceinline__ void split_bf(float x, unsigned short& h,
                                         unsigned short& l) {
  h = f2bf(x);
  l = f2bf(x - bf2f(h));
}
__device__ __forceinline__ uint2 pack4(const unsigned short h[4]) {
  return make_uint2((unsigned)h[0] | ((unsigned)h[1] << 16),
                    (unsigned)h[2] | ((unsigned)h[3] << 16));
}

// ---------- weight transpose+split: W[k][n] f32 -> Wt_h/Wt_l[n][k] bf16 -----
// scratch layout (ushort offsets):
// bW1t_h 0 (8192) | bW1t_l 8192 | bW2t_h 16384 (4096) | bW2t_l 20480
// bW3t_h 24576 (2048) | bW3t_l 26624 | aW1t_h 28672 (6144) | aW1t_l 34816
// aW2t_h 40960 (4096) | aW2t_l 45056 | aW3t_h 49152 (2048) | aW3t_l 51200
__global__ void wsplit_kernel(const float* __restrict__ bW1,
                              const float* __restrict__ bW2,
                              const float* __restrict__ bW3,
                              const float* __restrict__ aW1,
                              const float* __restrict__ aW2,
                              const float* __restrict__ aW3,
                              unsigned short* __restrict__ ws) {
  int i = blockIdx.x * blockDim.x + threadIdx.x;
  const float* src;
  unsigned short *dh, *dl;
  int K, N, base;
  if (i < 8192) {
    src = bW1; dh = ws; dl = ws + 8192; K = 128; N = 64; base = i;
  } else if (i < 12288) {
    src = bW2; dh = ws + 16384; dl = ws + 20480; K = 64; N = 64; base = i - 8192;
  } else if (i < 14336) {
    src = bW3; dh = ws + 24576; dl = ws + 26624; K = 64; N = 32; base = i - 12288;
  } else if (i < 20480) {
    src = aW1; dh = ws + 28672; dl = ws + 34816; K = 96; N = 64; base = i - 14336;
  } else if (i < 24576) {
    src = aW2; dh = ws + 40960; dl = ws + 45056; K = 64; N = 64; base = i - 20480;
  } else if (i < 26624) {
    src = aW3; dh = ws + 49152; dl = ws + 51200; K = 64; N = 32; base = i - 24576;
  } else {
    return;
  }
  int n = base / K, k = base - n * K;
  float v = src[k * N + n];
  unsigned short h, l;
  split_bf(v, h, l);
  dh[base] = h;
  dl[base] = l;
}

// ---------- shared MFMA tail: H1(softplus,split)->L2->H2->L3->out+atomics ---
// sb layout (ushort offsets): H1h 0 (64x72) | H1l 4608 | H2h 9216 | H2l 13824
// Caller must __syncthreads() before calling (X region is reused for H1).
__device__ __forceinline__ void mfma_tail(
    unsigned short* sb, int wv, int lr, int lq, f32x4 (&acc)[4],
    const unsigned short* __restrict__ W2h, const unsigned short* __restrict__ W2l,
    const unsigned short* __restrict__ W3h, const unsigned short* __restrict__ W3l,
    const float* __restrict__ B2, const float* __restrict__ B3,
    float* __restrict__ outp, long row0g, const int* ig,
    float* __restrict__ gsum, float* __restrict__ gcnt, int valid) {
  unsigned short* H1h = sb;         // [64][72]
  unsigned short* H1l = sb + 4608;
#pragma unroll
  for (int nt = 0; nt < 4; ++nt) {
#pragma unroll
    for (int r = 0; r < 4; ++r) {
      int row = 16 * wv + lq * 4 + r;
      int col = nt * 16 + lr;
      float v = softplus_f(acc[nt][r]);
      unsigned short h, l;
      split_bf(v, h, l);
      H1h[row * 72 + col] = h;
      H1l[row * 72 + col] = l;
    }
  }
  __syncthreads();

  f32x4 a2[4];
#pragma unroll
  for (int nt = 0; nt < 4; ++nt) {
    float b = B2[nt * 16 + lr];
    a2[nt] = (f32x4){b, b, b, b};
  }
  const unsigned short* hh = H1h + (16 * wv + lr) * 72 + lq * 8;
  const unsigned short* hl = H1l + (16 * wv + lr) * 72 + lq * 8;
#pragma unroll
  for (int t = 0; t < 2; ++t) {
    short8v Ah = *(const short8v*)(hh + t * 32);
    short8v Al = *(const short8v*)(hl + t * 32);
#pragma unroll
    for (int nt = 0; nt < 4; ++nt) {
      short8v Bh = *(const short8v*)(W2h + (nt * 16 + lr) * 64 + t * 32 + lq * 8);
      short8v Bl = *(const short8v*)(W2l + (nt * 16 + lr) * 64 + t * 32 + lq * 8);
      a2[nt] = MFMA_BF16(Ah, Bh, a2[nt]);
      a2[nt] = MFMA_BF16(Al, Bh, a2[nt]);
      a2[nt] = MFMA_BF16(Ah, Bl, a2[nt]);
    }
  }

  unsigned short* H2h = sb + 9216;
  unsigned short* H2l = sb + 13824;
#pragma unroll
  for (int nt = 0; nt < 4; ++nt) {
#pragma unroll
    for (int r = 0; r < 4; ++r) {
      int row = 16 * wv + lq * 4 + r;
      int col = nt * 16 + lr;
      float v = softplus_f(a2[nt][r]);
      unsigned short h, l;
      split_bf(v, h, l);
      H2h[row * 72 + col] = h;
      H2l[row * 72 + col] = l;
    }
  }
  __syncthreads();

  f32x4 a3[2];
#pragma unroll
  for (int nt = 0; nt < 2; ++nt) {
    float b = B3[nt * 16 + lr];
    a3[nt] = (f32x4){b, b, b, b};
  }
  const unsigned short* gh = H2h + (16 * wv + lr) * 72 + lq * 8;
  const unsigned short* gl = H2l + (16 * wv + lr) * 72 + lq * 8;
#pragma unroll
  for (int t = 0; t < 2; ++t) {
    short8v Ah = *(const short8v*)(gh + t * 32);
    short8v Al = *(const short8v*)(gl + t * 32);
#pragma unroll
    for (int nt = 0; nt < 2; ++nt) {
      short8v Bh = *(const short8v*)(W3h + (nt * 16 + lr) * 64 + t * 32 + lq * 8);
      short8v Bl = *(const short8v*)(W3l + (nt * 16 + lr) * 64 + t * 32 + lq * 8);
      a3[nt] = MFMA_BF16(Ah, Bh, a3[nt]);
      a3[nt] = MFMA_BF16(Al, Bh, a3[nt]);
      a3[nt] = MFMA_BF16(Ah, Bl, a3[nt]);
    }
  }

#pragma unroll
  for (int nt = 0; nt < 2; ++nt) {
#pragma unroll
    for (int r = 0; r < 4; ++r) {
      int row = 16 * wv + lq * 4 + r;
      if (row < valid) {
        int col = nt * 16 + lr;
        float v = a3[nt][r];
        outp[(row0g + row) * 32 + col] = v;
        atomicAdd(&gsum[(long)ig[row] * 32 + col], v);
      }
    }
  }
  if (lr == 0) {
#pragma unroll
    for (int r = 0; r < 4; ++r) {
      int row = 16 * wv + lq * 4 + r;
      if (row < valid) atomicAdd(&gcnt[ig[row]], 1.f);
    }
  }
}

// ---------------- atom MLP (K1 = 96: af | mean_bond | gf[amol]) -------------
__global__ void __launch_bounds__(TPB)
atom_mlp_kernel(const float* __restrict__ af, const float* __restrict__ bsum,
                const float* __restrict__ bcnt, const float* __restrict__ gf,
                const int* __restrict__ amol,
                const unsigned short* __restrict__ W1h,
                const unsigned short* __restrict__ W1l,  // [64][96]
                const unsigned short* __restrict__ W2h,
                const unsigned short* __restrict__ W2l,  // [64][64]
                const unsigned short* __restrict__ W3h,
                const unsigned short* __restrict__ W3l,  // [32][64]
                const float* __restrict__ B1, const float* __restrict__ B2,
                const float* __restrict__ B3, float* __restrict__ out_atom,
                float* __restrict__ gsum, float* __restrict__ gcnt, int NA) {
  __shared__ unsigned short sb[18432];  // 36864 B
  __shared__ int ig[64];
  __shared__ float rinv[64];
  const int tid = threadIdx.x;
  const long a0 = (long)blockIdx.x * 64;
  const int valid = (NA - a0 < 64) ? (int)(NA - a0) : 64;

  if (tid < 64) {
    long a = a0 + (tid < valid ? tid : 0);
    ig[tid] = amol[a];
    float c = bcnt[a];
    rinv[tid] = c > 0.f ? 1.f / c : 0.f;
  }
  __syncthreads();

  // stage X: 64 rows x 24 f4 slots -> Xh/Xl bf16, pitch 104
  unsigned short* Xh = sb;
  unsigned short* Xl = sb + 6656;
#pragma unroll
  for (int it = 0; it < 6; ++it) {
    int s = tid + it * TPB;  // < 1536
    int r = s / 24, slot = s - r * 24;
    int seg = slot >> 3, off = slot & 7;
    long arow = a0 + (r < valid ? r : 0);
    float4 v;
    if (seg == 0) {
      v = ((const float4*)af)[arow * 8 + off];
    } else if (seg == 1) {
      v = ((const float4*)bsum)[arow * 8 + off];
      float iv = rinv[r];
      v.x *= iv; v.y *= iv; v.z *= iv; v.w *= iv;
    } else {
      v = ((const float4*)gf)[(long)ig[r] * 8 + off];
    }
    unsigned short h[4], l[4];
    split_bf(v.x, h[0], l[0]);
    split_bf(v.y, h[1], l[1]);
    split_bf(v.z, h[2], l[2]);
    split_bf(v.w, h[3], l[3]);
    int k0 = slot * 4;
    *(uint2*)&Xh[r * 104 + k0] = pack4(h);
    *(uint2*)&Xl[r * 104 + k0] = pack4(l);
  }
  __syncthreads();

  const int wv = tid >> 6, ln = tid & 63, lr = ln & 15, lq = ln >> 4;
  f32x4 acc[4];
#pragma unroll
  for (int nt = 0; nt < 4; ++nt) {
    float b = B1[nt * 16 + lr];
    acc[nt] = (f32x4){b, b, b, b};
  }
  const unsigned short* xh = Xh + (16 * wv + lr) * 104 + lq * 8;
  const unsigned short* xl = Xl + (16 * wv + lr) * 104 + lq * 8;
#pragma unroll
  for (int t = 0; t < 3; ++t) {
    short8v Ah = *(const short8v*)(xh + t * 32);
    short8v Al = *(const short8v*)(xl + t * 32);
#pragma unroll
    for (int nt = 0; nt < 4; ++nt) {
      short8v Bh = *(const short8v*)(W1h + (nt * 16 + lr) * 96 + t * 32 + lq * 8);
      short8v Bl = *(const short8v*)(W1l + (nt * 16 + lr) * 96 + t * 32 + lq * 8);
      acc[nt] = MFMA_BF16(Ah, Bh, acc[nt]);
      acc[nt] = MFMA_BF16(Al, Bh, acc[nt]);
      acc[nt] = MFMA_BF16(Ah, Bl, acc[nt]);
    }
  }
  __syncthreads();  // X dead; sb reused for H1/H2
  mfma_tail(sb, wv, lr, lq, acc, W2h, W2l, W3h, W3l, B2, B3, out_atom, a0, ig,
            gsum, gcnt, valid);
}

// ---------------- bond MLP (K1 = 128: bf | a0 | a1 | gf[bmol]) --------------
__global__ void __launch_bounds__(TPB)
bond_mlp_kernel(const float* __restrict__ bf, const float* __restrict__ atom_new,
                const float* __restrict__ gf, const int* __restrict__ ba,
                const int* __restrict__ bmol,
                const unsigned short* __restrict__ W1h,
                const unsigned short* __restrict__ W1l,  // [64][128]
                const unsigned short* __restrict__ W2h,
                const unsigned short* __restrict__ W2l,  // [64][64]
                const unsigned short* __restrict__ W3h,
                const unsigned short* __restrict__ W3l,  // [32][64]
                const float* __restrict__ B1, const float* __restrict__ B2,
                const float* __restrict__ B3, float* __restrict__ out_bond,
                float* __restrict__ gsum, float* __restrict__ gcnt, int NB) {
  __shared__ unsigned short sb[18432];  // 36864 B
  __shared__ int ia0[64], ia1[64], ig[64];
  const int tid = threadIdx.x;
  const long b0 = (long)blockIdx.x * 64;
  const int valid = (NB - b0 < 64) ? (int)(NB - b0) : 64;

  if (tid < 64) {
    long b = b0 + (tid < valid ? tid : 0);
    ia0[tid] = ba[2 * b];
    ia1[tid] = ba[2 * b + 1];
    ig[tid] = bmol[b];
  }
  __syncthreads();

  // stage X: 64 rows x 32 f4 slots -> Xh/Xl bf16, pitch 136
  unsigned short* Xh = sb;
  unsigned short* Xl = sb + 8704;
#pragma unroll
  for (int it = 0; it < 8; ++it) {
    int s = tid + it * TPB;  // < 2048
    int r = s >> 5, slot = s & 31;
    int seg = slot >> 3, off = slot & 7;
    long brow = b0 + (r < valid ? r : 0);
    const float4* src;
    if (seg == 0)      src = (const float4*)bf + (brow * 8 + off);
    else if (seg == 1) src = (const float4*)atom_new + ((long)ia0[r] * 8 + off);
    else if (seg == 2) src = (const float4*)atom_new + ((long)ia1[r] * 8 + off);
    else               src = (const float4*)gf + ((long)ig[r] * 8 + off);
    float4 v = *src;
    unsigned short h[4], l[4];
    split_bf(v.x, h[0], l[0]);
    split_bf(v.y, h[1], l[1]);
    split_bf(v.z, h[2], l[2]);
    split_bf(v.w, h[3], l[3]);
    int k0 = slot * 4;
    *(uint2*)&Xh[r * 136 + k0] = pack4(h);
    *(uint2*)&Xl[r * 136 + k0] = pack4(l);
  }
  __syncthreads();

  const int wv = tid >> 6, ln = tid & 63, lr = ln & 15, lq = ln >> 4;
  f32x4 acc[4];
#pragma unroll
  for (int nt = 0; nt < 4; ++nt) {
    float b = B1[nt * 16 + lr];
    acc[nt] = (f32x4){b, b, b, b};
  }
  const unsigned short* xh = Xh + (16 * wv + lr) * 136 + lq * 8;
  const unsigned short* xl = Xl + (16 * wv + lr) * 136 + lq * 8;
#pragma unroll
  for (int t = 0; t < 4; ++t) {
    short8v Ah = *(const short8v*)(xh + t * 32);
    short8v Al = *(const short8v*)(xl + t * 32);
#pragma unroll
    for (int nt = 0; nt < 4; ++nt) {
      short8v Bh = *(const short8v*)(W1h + (nt * 16 + lr) * 128 + t * 32 + lq * 8);
      short8v Bl = *(const short8v*)(W1l + (nt * 16 + lr) * 128 + t * 32 + lq * 8);
      acc[nt] = MFMA_BF16(Ah, Bh, acc[nt]);
      acc[nt] = MFMA_BF16(Al, Bh, acc[nt]);
      acc[nt] = MFMA_BF16(Ah, Bl, acc[nt]);
    }
  }
  __syncthreads();  // X dead; sb reused for H1/H2
  mfma_tail(sb, wv, lr, lq, acc, W2h, W2l, W3h, W3l, B2, B3, out_bond, b0, ig,
            gsum, gcnt, valid);
}

// ---------------- glob MLP (VALU per-row; NG is small) ----------------------
__device__ __forceinline__ void l1_chunk(float h1[64],
                                         const float* __restrict__ xrow,
                                         float scale,
                                         const float* __restrict__ Wrow) {
#pragma unroll 4
  for (int k = 0; k < 32; ++k) {
    float xv = xrow[k] * scale;
#pragma unroll
    for (int j = 0; j < 64; ++j) h1[j] = fmaf(xv, Wrow[k * 64 + j], h1[j]);
  }
}

__device__ __forceinline__ void mlp_tail_valu(float h1[64],
                                              const float* __restrict__ W2,
                                              const float* __restrict__ B2,
                                              const float* __restrict__ W3,
                                              const float* __restrict__ B3,
                                              float o[32]) {
#pragma unroll
  for (int j = 0; j < 64; ++j) h1[j] = softplus_f(h1[j]);
  float h2[64];
#pragma unroll
  for (int j = 0; j < 64; ++j) h2[j] = B2[j];
#pragma unroll
  for (int k = 0; k < 64; ++k) {
    float xv = h1[k];
#pragma unroll
    for (int j = 0; j < 64; ++j) h2[j] = fmaf(xv, W2[k * 64 + j], h2[j]);
  }
#pragma unroll
  for (int j = 0; j < 64; ++j) h2[j] = softplus_f(h2[j]);
#pragma unroll
  for (int j = 0; j < 32; ++j) o[j] = B3[j];
#pragma unroll
  for (int k = 0; k < 64; ++k) {
    float xv = h2[k];
#pragma unroll
    for (int j = 0; j < 32; ++j) o[j] = fmaf(xv, W3[k * 32 + j], o[j]);
  }
}

__global__ void __launch_bounds__(TPB)
glob_mlp_kernel(const float* __restrict__ gf, const float* __restrict__ asum,
                const float* __restrict__ acnt, const float* __restrict__ bsum,
                const float* __restrict__ bcnt,
                const float* __restrict__ W1, const float* __restrict__ B1,
                const float* __restrict__ W2, const float* __restrict__ B2,
                const float* __restrict__ W3, const float* __restrict__ B3,
                float* __restrict__ out_glob, int NG) {
  int m = blockIdx.x * TPB + threadIdx.x;
  if (m >= NG) return;
  float h1[64];
#pragma unroll
  for (int j = 0; j < 64; ++j) h1[j] = B1[j];
  l1_chunk(h1, gf + (long)m * 32, 1.f, W1);
  float ca = acnt[m];
  float inva = ca > 0.f ? 1.f / ca : 0.f;
  l1_chunk(h1, asum + (long)m * 32, inva, W1 + 32 * 64);
  float cb = bcnt[m];
  float invb = cb > 0.f ? 1.f / cb : 0.f;
  l1_chunk(h1, bsum + (long)m * 32, invb, W1 + 64 * 64);
  float o[32];
  mlp_tail_valu(h1, W2, B2, W3, B3, o);
  float4* dst = (float4*)(out_glob + (long)m * 32);
#pragma unroll
  for (int q = 0; q < 8; ++q)
    dst[q] = make_float4(o[4 * q], o[4 * q + 1], o[4 * q + 2], o[4 * q + 3]);
}

extern "C" void kernel_launch(void* const* d_in, const int* in_sizes, int n_in,
                              void* d_out, int out_size, void* d_ws, size_t ws_size,
                              hipStream_t stream) {
  const float* af = (const float*)d_in[0];
  const float* bf = (const float*)d_in[1];
  const float* gf = (const float*)d_in[2];
  const int* ba = (const int*)d_in[3];
  const int* amol = (const int*)d_in[4];
  const int* bmol = (const int*)d_in[5];
  const float* aW1 = (const float*)d_in[6];
  const float* ab1 = (const float*)d_in[7];
  const float* aW2 = (const float*)d_in[8];
  const float* ab2 = (const float*)d_in[9];
  const float* aW3 = (const float*)d_in[10];
  const float* ab3 = (const float*)d_in[11];
  const float* bW1 = (const float*)d_in[12];
  const float* bb1 = (const float*)d_in[13];
  const float* bW2 = (const float*)d_in[14];
  const float* bb2 = (const float*)d_in[15];
  const float* bW3 = (const float*)d_in[16];
  const float* bb3 = (const float*)d_in[17];
  const float* gW1 = (const float*)d_in[18];
  const float* gb1 = (const float*)d_in[19];
  const float* gW2 = (const float*)d_in[20];
  const float* gb2 = (const float*)d_in[21];
  const float* gW3 = (const float*)d_in[22];
  const float* gb3 = (const float*)d_in[23];

  const int NA = in_sizes[0] / 32;
  const int NB = in_sizes[1] / 32;
  const int NG = in_sizes[2] / 32;

  float* out = (float*)d_out;
  float* out_atom = out;
  float* out_bond = out + (long)NA * 32;
  float* out_glob = out + (long)NA * 32 + (long)NB * 32;

  // bond_sum scratch reuses the bond_new output region.
  float* bsum = out_bond;
  float* ws = (float*)d_ws;
  float* bcnt = ws;                        // [NA]
  float* asumg = bcnt + (long)NA;          // [NG*32]
  float* acntg = asumg + (long)NG * 32;    // [NG]
  float* bsumg = acntg + (long)NG;         // [NG*32]
  float* bcntg = bsumg + (long)NG * 32;    // [NG]

  // weight bf16-split scratch carved from out_glob (written last by glob mlp)
  unsigned short* wscr = (unsigned short*)out_glob;
  const unsigned short* bW1h = wscr;
  const unsigned short* bW1l = wscr + 8192;
  const unsigned short* bW2h = wscr + 16384;
  const unsigned short* bW2l = wscr + 20480;
  const unsigned short* bW3h = wscr + 24576;
  const unsigned short* bW3l = wscr + 26624;
  const unsigned short* aW1h = wscr + 28672;
  const unsigned short* aW1l = wscr + 34816;
  const unsigned short* aW2h = wscr + 40960;
  const unsigned short* aW2l = wscr + 45056;
  const unsigned short* aW3h = wscr + 49152;
  const unsigned short* aW3l = wscr + 51200;

  long z1 = ((long)NA * 32) / 4;                 // bond_sum floats /4
  long z2 = ((long)NA + (long)NG * 66 + 3) / 4;  // ws floats /4
  zero4_kernel<<<dim3(2048), dim3(TPB), 0, stream>>>((float4*)bsum, z1);
  zero4_kernel<<<dim3(2048), dim3(TPB), 0, stream>>>((float4*)ws, z2);

  wsplit_kernel<<<dim3(104), dim3(TPB), 0, stream>>>(bW1, bW2, bW3, aW1, aW2,
                                                     aW3, wscr);

  long nscatter = (long)NB * 32;
  scatter_bonds_kernel<<<dim3((nscatter + TPB - 1) / TPB), dim3(TPB), 0, stream>>>(
      bf, ba, bsum, bcnt, NB);

  atom_mlp_kernel<<<dim3((NA + 63) / 64), dim3(TPB), 0, stream>>>(
      af, bsum, bcnt, gf, amol, aW1h, aW1l, aW2h, aW2l, aW3h, aW3l, ab1, ab2,
      ab3, out_atom, asumg, acntg, NA);

  bond_mlp_kernel<<<dim3((NB + 63) / 64), dim3(TPB), 0, stream>>>(
      bf, out_atom, gf, ba, bmol, bW1h, bW1l, bW2h, bW2l, bW3h, bW3l, bb1, bb2,
      bb3, out_bond, bsumg, bcntg, NB);

  glob_mlp_kernel<<<dim3((NG + TPB - 1) / TPB), dim3(TPB), 0, stream>>>(
      gf, asumg, acntg, bsumg, bcntg, gW1, gb1, gW2, gb2, gW3, gb3, out_glob,
      NG);
}